// Round 1
// baseline (1354.817 us; speedup 1.0000x reference)
//
#include <hip/hip_runtime.h>
#include <math.h>

// B=4096, S=128, F=8, H1=64, H2=32
// Stage A: x1 = relu(concat(x,time) @ Wc^T + bc)   [4096][1024] -> d_ws
// Stage B: fused LSTM1 -> LSTM2 -> out projection

__device__ __forceinline__ float sigm(float x) { return 1.f / (1.f + __expf(-x)); }
__device__ __forceinline__ float tanh_fast(float x) {
  x = fminf(fmaxf(x, -15.f), 15.f);
  float e = __expf(2.f * x);
  return (e - 1.f) / (e + 1.f);
}

// ---------------- Kernel A: combine GEMM + relu ----------------
// M=4096 (batch), N=1024 (out), K=1024 main + time column (K idx 1024)
__global__ __launch_bounds__(256) void combine_gemm(
    const float* __restrict__ x, const float* __restrict__ tme,
    const float* __restrict__ Wc, const float* __restrict__ bc,
    float* __restrict__ x1)
{
  __shared__ float As[16][132];
  __shared__ float Bs[16][132];
  const int tid = threadIdx.x;
  const int tx = tid & 15, ty = tid >> 4;
  const int M0 = blockIdx.y * 128, N0 = blockIdx.x * 128;
  const int r0 = ty * 8, c0 = tx * 8;
  float acc[8][8];
#pragma unroll
  for (int i = 0; i < 8; ++i)
#pragma unroll
    for (int j = 0; j < 8; ++j) acc[i][j] = 0.f;

  for (int kt = 0; kt < 1024; kt += 16) {
#pragma unroll
    for (int i = 0; i < 8; ++i) {
      int idx = tid + i * 256;
      int r = idx >> 4, kk = idx & 15;
      As[kk][r] = x[(size_t)(M0 + r) * 1024 + kt + kk];
      Bs[kk][r] = Wc[(size_t)(N0 + r) * 1025 + kt + kk];
    }
    __syncthreads();
#pragma unroll
    for (int kk = 0; kk < 16; ++kk) {
      float4 a0 = *(const float4*)&As[kk][r0];
      float4 a1 = *(const float4*)&As[kk][r0 + 4];
      float4 b0 = *(const float4*)&Bs[kk][c0];
      float4 b1 = *(const float4*)&Bs[kk][c0 + 4];
      float av[8] = {a0.x, a0.y, a0.z, a0.w, a1.x, a1.y, a1.z, a1.w};
      float bv[8] = {b0.x, b0.y, b0.z, b0.w, b1.x, b1.y, b1.z, b1.w};
#pragma unroll
      for (int i = 0; i < 8; ++i)
#pragma unroll
        for (int j = 0; j < 8; ++j)
          acc[i][j] += av[i] * bv[j];
    }
    __syncthreads();
  }

  float wlast[8], bcv[8];
#pragma unroll
  for (int j = 0; j < 8; ++j) {
    int o = N0 + c0 + j;
    wlast[j] = Wc[(size_t)o * 1025 + 1024];
    bcv[j] = bc[o];
  }
#pragma unroll
  for (int i = 0; i < 8; ++i) {
    int b = M0 + r0 + i;
    float tv = tme[b];
    float o8[8];
#pragma unroll
    for (int j = 0; j < 8; ++j)
      o8[j] = fmaxf(acc[i][j] + tv * wlast[j] + bcv[j], 0.f);
    float4 s0 = {o8[0], o8[1], o8[2], o8[3]};
    float4 s1 = {o8[4], o8[5], o8[6], o8[7]};
    *(float4*)&x1[(size_t)b * 1024 + N0 + c0] = s0;
    *(float4*)&x1[(size_t)b * 1024 + N0 + c0 + 4] = s1;
  }
}

// ---------------- Kernel B: fused LSTM1+LSTM2+out ----------------
// 256 blocks x 256 threads, 16 batches per block (1 block/CU).
// All weights in LDS, gate-interleaved [k][h*4+gate]; state transposed [h][b],
// double buffered; 2 barriers per timestep.
__global__ __launch_bounds__(256) void lstm_fused(
    const float* __restrict__ x1,
    const float* __restrict__ Wih1, const float* __restrict__ Whh1,
    const float* __restrict__ Wih2, const float* __restrict__ Whh2,
    const float* __restrict__ bih2, const float* __restrict__ bhh2,
    const float* __restrict__ Wout, const float* __restrict__ bout,
    float* __restrict__ out)
{
  extern __shared__ float sm[];
  float* sW1T  = sm;                 // [64][256]  Whh1^T gate-interleaved
  float* sWi1T = sW1T + 64 * 256;    // [8][256]
  float* sWi2T = sWi1T + 8 * 256;    // [64][128]
  float* sWh2T = sWi2T + 64 * 128;   // [32][128]
  float* sb2   = sWh2T + 32 * 128;   // [128]
  float* sh1   = sb2 + 128;          // [2][64][20] h1 state, [h][b], dbuf
  float* sh2   = sh1 + 2 * 64 * 20;  // [2][32][20]
  float* sxT   = sh2 + 2 * 32 * 20;  // [8][20]     x tile, [d][b]

  const int tid = threadIdx.x;
  const int b0 = blockIdx.x * 16;

  // ---- preload weights (once) ----
  for (int idx = tid; idx < 64 * 256; idx += 256) {
    int j = idx & 255, k = idx >> 8;
    int h = j >> 2, gi = j & 3;
    sW1T[idx] = Whh1[(gi * 64 + h) * 64 + k];
  }
  for (int idx = tid; idx < 8 * 256; idx += 256) {
    int j = idx & 255, d = idx >> 8;
    int h = j >> 2, gi = j & 3;
    sWi1T[idx] = Wih1[(gi * 64 + h) * 8 + d];
  }
  for (int idx = tid; idx < 64 * 128; idx += 256) {
    int j = idx & 127, k = idx >> 7;
    int h = j >> 2, gi = j & 3;
    sWi2T[idx] = Wih2[(gi * 32 + h) * 64 + k];
  }
  for (int idx = tid; idx < 32 * 128; idx += 256) {
    int j = idx & 127, k = idx >> 7;
    int h = j >> 2, gi = j & 3;
    sWh2T[idx] = Whh2[(gi * 32 + h) * 32 + k];
  }
  if (tid < 128) {
    int h = tid >> 2, gi = tid & 3;
    sb2[tid] = bih2[gi * 32 + h] + bhh2[gi * 32 + h];
  }
  for (int idx = tid; idx < 2 * 64 * 20 + 2 * 32 * 20 + 8 * 20; idx += 256)
    sh1[idx] = 0.f;
  __syncthreads();

  // phase-1 mapping: lane jj = h index (0..63), wave bg owns 4 batches
  const int jj = tid & 63;
  const int bg = tid >> 6;          // 0..3, uniform per wave
  // phase-2 mapping: jj2 = h2 index (0..31), bh picks 2 of the wave's 4 batches
  const int jj2 = tid & 31;
  const int bh = (tid >> 5) & 1;
  // x staging (tid < 128)
  const int bb = tid >> 3;
  const int dd = tid & 7;

  float c1[4] = {0.f, 0.f, 0.f, 0.f};
  float c2[2] = {0.f, 0.f};
  float accO[2] = {0.f, 0.f};
  int cur = 0;

  for (int t = 0; t < 128; ++t) {
    if (tid < 128)
      sxT[dd * 20 + bb] = x1[(size_t)(b0 + bb) * 1024 + t * 8 + dd];
    __syncthreads();   // sxT ready; prev-step sh2 writes visible

    // ---- phase 1: LSTM layer 1 ----
    const float* sh1c = sh1 + cur * 1280;
    float* sh1n = sh1 + (cur ^ 1) * 1280;
    float g[4][4];
#pragma unroll
    for (int i = 0; i < 4; ++i) { g[i][0] = 0.f; g[i][1] = 0.f; g[i][2] = 0.f; g[i][3] = 0.f; }
#pragma unroll
    for (int d = 0; d < 8; ++d) {
      const float4 xv = *(const float4*)&sxT[d * 20 + bg * 4];
      const float4 w = *(const float4*)&sWi1T[d * 256 + jj * 4];
      const float xa[4] = {xv.x, xv.y, xv.z, xv.w};
#pragma unroll
      for (int i = 0; i < 4; ++i) {
        g[i][0] += xa[i] * w.x; g[i][1] += xa[i] * w.y;
        g[i][2] += xa[i] * w.z; g[i][3] += xa[i] * w.w;
      }
    }
#pragma unroll 8
    for (int k = 0; k < 64; ++k) {
      const float4 hv = *(const float4*)&sh1c[k * 20 + bg * 4];
      const float4 w = *(const float4*)&sW1T[k * 256 + jj * 4];
      const float ha[4] = {hv.x, hv.y, hv.z, hv.w};
#pragma unroll
      for (int i = 0; i < 4; ++i) {
        g[i][0] += ha[i] * w.x; g[i][1] += ha[i] * w.y;
        g[i][2] += ha[i] * w.z; g[i][3] += ha[i] * w.w;
      }
    }
    float h1n[4];
#pragma unroll
    for (int i = 0; i < 4; ++i) {
      float ig = sigm(g[i][0]);
      float fg = sigm(g[i][1]);
      float gg = tanh_fast(g[i][2]);
      float og = sigm(g[i][3]);
      c1[i] = fg * c1[i] + ig * gg;
      h1n[i] = og * tanh_fast(c1[i]);
    }
    *(float4*)&sh1n[jj * 20 + bg * 4] = make_float4(h1n[0], h1n[1], h1n[2], h1n[3]);
    __syncthreads();   // h1 new visible

    // ---- phase 2: LSTM layer 2 + out accum ----
    const float* sh2c = sh2 + cur * 640;
    float* sh2n = sh2 + (cur ^ 1) * 640;
    float g2[2][4];
    {
      const float4 bv = *(const float4*)&sb2[jj2 * 4];
#pragma unroll
      for (int i = 0; i < 2; ++i) { g2[i][0] = bv.x; g2[i][1] = bv.y; g2[i][2] = bv.z; g2[i][3] = bv.w; }
    }
#pragma unroll 8
    for (int k = 0; k < 64; ++k) {
      const float2 hv = *(const float2*)&sh1n[k * 20 + bg * 4 + bh * 2];
      const float4 w = *(const float4*)&sWi2T[k * 128 + jj2 * 4];
      g2[0][0] += hv.x * w.x; g2[0][1] += hv.x * w.y; g2[0][2] += hv.x * w.z; g2[0][3] += hv.x * w.w;
      g2[1][0] += hv.y * w.x; g2[1][1] += hv.y * w.y; g2[1][2] += hv.y * w.z; g2[1][3] += hv.y * w.w;
    }
#pragma unroll 8
    for (int k = 0; k < 32; ++k) {
      const float2 hv = *(const float2*)&sh2c[k * 20 + bg * 4 + bh * 2];
      const float4 w = *(const float4*)&sWh2T[k * 128 + jj2 * 4];
      g2[0][0] += hv.x * w.x; g2[0][1] += hv.x * w.y; g2[0][2] += hv.x * w.z; g2[0][3] += hv.x * w.w;
      g2[1][0] += hv.y * w.x; g2[1][1] += hv.y * w.y; g2[1][2] += hv.y * w.z; g2[1][3] += hv.y * w.w;
    }
    const float wo = Wout[t * 32 + jj2];
    float h2n[2];
#pragma unroll
    for (int i = 0; i < 2; ++i) {
      float ig = sigm(g2[i][0]);
      float fg = sigm(g2[i][1]);
      float gg = tanh_fast(g2[i][2]);
      float og = sigm(g2[i][3]);
      c2[i] = fg * c2[i] + ig * gg;
      h2n[i] = og * tanh_fast(c2[i]);
      accO[i] += h2n[i] * wo;
    }
    *(float2*)&sh2n[jj2 * 20 + bg * 4 + bh * 2] = make_float2(h2n[0], h2n[1]);
    cur ^= 1;
    // no barrier here: next-iter top barrier covers sh2n visibility
  }

  // reduce over jj2 lanes within each 32-lane group
#pragma unroll
  for (int off = 16; off >= 1; off >>= 1) {
    accO[0] += __shfl_xor(accO[0], off, 32);
    accO[1] += __shfl_xor(accO[1], off, 32);
  }
  if (jj2 == 0) {
    const float bo = bout[0];
    out[b0 + bg * 4 + bh * 2 + 0] = accO[0] + bo;
    out[b0 + bg * 4 + bh * 2 + 1] = accO[1] + bo;
  }
}

extern "C" void kernel_launch(void* const* d_in, const int* in_sizes, int n_in,
                              void* d_out, int out_size, void* d_ws, size_t ws_size,
                              hipStream_t stream) {
  const float* x    = (const float*)d_in[0];
  const float* tme  = (const float*)d_in[1];
  const float* Wc   = (const float*)d_in[2];
  const float* bc   = (const float*)d_in[3];
  const float* Wih1 = (const float*)d_in[4];
  const float* Whh1 = (const float*)d_in[5];
  const float* Wih2 = (const float*)d_in[6];
  const float* Whh2 = (const float*)d_in[7];
  const float* bih2 = (const float*)d_in[8];
  const float* bhh2 = (const float*)d_in[9];
  const float* Wout = (const float*)d_in[10];
  const float* bout = (const float*)d_in[11];
  float* outp = (float*)d_out;
  float* x1 = (float*)d_ws;  // [4096][1024] f32 = 16.78 MB

  dim3 gA(8, 32);  // N/128, M/128
  combine_gemm<<<gA, 256, 0, stream>>>(x, tme, Wc, bc, x1);

  const size_t smem = (size_t)(64 * 256 + 8 * 256 + 64 * 128 + 32 * 128 + 128
                               + 2 * 64 * 20 + 2 * 32 * 20 + 8 * 20) * sizeof(float);
  // opt-in for >64KB dynamic LDS (idempotent, deterministic)
  hipFuncSetAttribute(reinterpret_cast<const void*>(lstm_fused),
                      hipFuncAttributeMaxDynamicSharedMemorySize, (int)smem);
  lstm_fused<<<256, 256, smem, stream>>>(x1, Wih1, Whh1, Wih2, Whh2,
                                         bih2, bhh2, Wout, bout, outp);
}

// Round 2
// 435.631 us; speedup vs baseline: 3.1100x; 3.1100x over previous
//
#include <hip/hip_runtime.h>
#include <math.h>

// B=4096, S=128, F=8, H1=64, H2=32
// Stage A: x1 = relu(concat(x,time) @ Wc^T + bc)   [4096][1024] f32 -> d_ws
// Stage B: fused LSTM1 -> LSTM2 -> out projection, MFMA bf16 split-state

typedef __bf16 bf16x8 __attribute__((ext_vector_type(8)));
typedef float f32x4 __attribute__((ext_vector_type(4)));

union F8 { uint4 q; unsigned u[4]; bf16x8 v; };

__device__ __forceinline__ float sigm(float x) { return 1.f / (1.f + __expf(-x)); }
__device__ __forceinline__ float tanh_fast(float x) {
  x = fminf(fmaxf(x, -15.f), 15.f);
  float e = __expf(2.f * x);
  return (e - 1.f) / (e + 1.f);
}

// split f32 into bf16 hi (trunc) + bf16 lo (residual), packed lo<<16|hi
__device__ __forceinline__ unsigned split_pack(float x) {
  unsigned u = __float_as_uint(x);
  float hif = __uint_as_float(u & 0xffff0000u);
  float lo = x - hif;
  return (u >> 16) | (__float_as_uint(lo) & 0xffff0000u);
}

// bf16 RNE of w, duplicated into both halves of a u32
__device__ __forceinline__ unsigned dup_bf(float w) {
  unsigned u = __float_as_uint(w);
  unsigned b = (u + 0x7fffu + ((u >> 16) & 1u)) >> 16;
  return b | (b << 16);
}

__device__ __forceinline__ F8 dup_frag(float4 w) {
  F8 f;
  f.u[0] = dup_bf(w.x); f.u[1] = dup_bf(w.y);
  f.u[2] = dup_bf(w.z); f.u[3] = dup_bf(w.w);
  return f;
}

// ---------------- Kernel A: combine GEMM + relu (f32, at vector roofline) ----
__global__ __launch_bounds__(256) void combine_gemm(
    const float* __restrict__ x, const float* __restrict__ tme,
    const float* __restrict__ Wc, const float* __restrict__ bc,
    float* __restrict__ x1)
{
  __shared__ float As[16][132];
  __shared__ float Bs[16][132];
  const int tid = threadIdx.x;
  const int tx = tid & 15, ty = tid >> 4;
  const int M0 = blockIdx.y * 128, N0 = blockIdx.x * 128;
  const int r0 = ty * 8, c0 = tx * 8;
  float acc[8][8];
#pragma unroll
  for (int i = 0; i < 8; ++i)
#pragma unroll
    for (int j = 0; j < 8; ++j) acc[i][j] = 0.f;

  for (int kt = 0; kt < 1024; kt += 16) {
#pragma unroll
    for (int i = 0; i < 8; ++i) {
      int idx = tid + i * 256;
      int r = idx >> 4, kk = idx & 15;
      As[kk][r] = x[(size_t)(M0 + r) * 1024 + kt + kk];
      Bs[kk][r] = Wc[(size_t)(N0 + r) * 1025 + kt + kk];
    }
    __syncthreads();
#pragma unroll
    for (int kk = 0; kk < 16; ++kk) {
      float4 a0 = *(const float4*)&As[kk][r0];
      float4 a1 = *(const float4*)&As[kk][r0 + 4];
      float4 b0 = *(const float4*)&Bs[kk][c0];
      float4 b1 = *(const float4*)&Bs[kk][c0 + 4];
      float av[8] = {a0.x, a0.y, a0.z, a0.w, a1.x, a1.y, a1.z, a1.w};
      float bv[8] = {b0.x, b0.y, b0.z, b0.w, b1.x, b1.y, b1.z, b1.w};
#pragma unroll
      for (int i = 0; i < 8; ++i)
#pragma unroll
        for (int j = 0; j < 8; ++j)
          acc[i][j] += av[i] * bv[j];
    }
    __syncthreads();
  }

  float wlast[8], bcv[8];
#pragma unroll
  for (int j = 0; j < 8; ++j) {
    int o = N0 + c0 + j;
    wlast[j] = Wc[(size_t)o * 1025 + 1024];
    bcv[j] = bc[o];
  }
#pragma unroll
  for (int i = 0; i < 8; ++i) {
    int b = M0 + r0 + i;
    float tv = tme[b];
    float o8[8];
#pragma unroll
    for (int j = 0; j < 8; ++j)
      o8[j] = fmaxf(acc[i][j] + tv * wlast[j] + bcv[j], 0.f);
    float4 s0 = {o8[0], o8[1], o8[2], o8[3]};
    float4 s1 = {o8[4], o8[5], o8[6], o8[7]};
    *(float4*)&x1[(size_t)b * 1024 + N0 + c0] = s0;
    *(float4*)&x1[(size_t)b * 1024 + N0 + c0 + 4] = s1;
  }
}

// ---------------- Kernel B: fused LSTM via MFMA -----------------------------
// 256 blocks x 256 threads (4 waves), 16 batches/block, 1 block/CU.
// Weights live in VGPRs (B-frags, built once). State hi/lo split, interleaved
// along k' (k'=2h:hi, 2h+1:lo), both slots paired with the same bf16 weight.
// LDS state [batch][k'] bf16; A-frag = ds_read_b128; writes = 4x ds_write_b32.
__global__ __launch_bounds__(256, 1) void lstm_fused_mfma(
    const float* __restrict__ x1,
    const float* __restrict__ Wih1, const float* __restrict__ Whh1,
    const float* __restrict__ Wih2, const float* __restrict__ Whh2,
    const float* __restrict__ bih2, const float* __restrict__ bhh2,
    const float* __restrict__ Wout, const float* __restrict__ bout,
    float* __restrict__ out)
{
  __shared__ float sWo[4096];                               // Wout, 16 KB
  __shared__ __align__(16) unsigned short sh1[2][16][136];  // [buf][batch][k'=128+8]
  __shared__ __align__(16) unsigned short sh2[2][16][72];   // [buf][batch][k'=64+8]
  __shared__ float sOut[32];

  const int tid = threadIdx.x;
  const int lane = tid & 63;
  const int wid = tid >> 6;     // wave id 0..3
  const int col = lane & 15;    // tile col (= h within range) / A row (= batch)
  const int grp = lane >> 4;    // k-slot group
  const int b0 = blockIdx.x * 16;

  // ---- one-time: weight B-fragments into registers ----
  // layer1: wave wid owns h in [16*wid, 16*wid+16), gate tiles gi=i,f,g,o
  bf16x8 B1[4][4];  // [gate][chunk]  Whh1 part, k' chunks of 32 (16 h each)
  bf16x8 Bx[4];     // [gate]         x part (8 dims -> slots 0..15, rest 0)
#pragma unroll
  for (int gi = 0; gi < 4; ++gi) {
    const int row = gi * 64 + wid * 16 + col;
#pragma unroll
    for (int c = 0; c < 4; ++c) {
      float4 w = *(const float4*)&Whh1[row * 64 + c * 16 + grp * 4];
      B1[gi][c] = dup_frag(w).v;
    }
    float4 xw = make_float4(0.f, 0.f, 0.f, 0.f);
    if (grp < 2) xw = *(const float4*)&Wih1[row * 8 + grp * 4];
    Bx[gi] = dup_frag(xw).v;
  }
  // layer2: waves 0,1 own h2 in [16*wid, 16*wid+16)
  bf16x8 B2a[4][4];  // Wih2 (k=h1, 64 -> 4 chunks)
  bf16x8 B2b[4][2];  // Whh2 (k=h2, 32 -> 2 chunks)
  float bias2[4] = {0.f, 0.f, 0.f, 0.f};
  if (wid < 2) {
#pragma unroll
    for (int gi = 0; gi < 4; ++gi) {
      const int row = gi * 32 + wid * 16 + col;
#pragma unroll
      for (int c = 0; c < 4; ++c) {
        float4 w = *(const float4*)&Wih2[row * 64 + c * 16 + grp * 4];
        B2a[gi][c] = dup_frag(w).v;
      }
#pragma unroll
      for (int c = 0; c < 2; ++c) {
        float4 w = *(const float4*)&Whh2[row * 32 + c * 16 + grp * 4];
        B2b[gi][c] = dup_frag(w).v;
      }
      bias2[gi] = bih2[row] + bhh2[row];
    }
  }

  // ---- one-time: LDS init ----
  for (int i = tid; i < 4096; i += 256) sWo[i] = Wout[i];
  {
    unsigned short* z = &sh1[0][0][0];
    for (int i = tid; i < 2 * 16 * 136; i += 256) z[i] = 0;
    unsigned short* z2 = &sh2[0][0][0];
    for (int i = tid; i < 2 * 16 * 72; i += 256) z2[i] = 0;
  }
  __syncthreads();

  // x prefetch: lane's batch = col (A-frag row); 8 f32 per step
  const float* xrow = x1 + (size_t)(b0 + col) * 1024;
  float4 xpA = *(const float4*)&xrow[0];
  float4 xpB = *(const float4*)&xrow[4];

  float c1[4] = {0.f, 0.f, 0.f, 0.f};
  float c2[4] = {0.f, 0.f, 0.f, 0.f};
  f32x4 accO = {0.f, 0.f, 0.f, 0.f};
  int cur = 0;

  for (int t = 0; t < 128; ++t) {
    // build x A-frag (hi/lo interleaved, grp0: dims 0-3, grp1: dims 4-7)
    float xs[8] = {xpA.x, xpA.y, xpA.z, xpA.w, xpB.x, xpB.y, xpB.z, xpB.w};
    unsigned xp[8];
#pragma unroll
    for (int d = 0; d < 8; ++d) xp[d] = split_pack(xs[d]);
    F8 ax;
#pragma unroll
    for (int j = 0; j < 4; ++j)
      ax.u[j] = (grp == 0) ? xp[j] : (grp == 1) ? xp[4 + j] : 0u;

    // ---- phase 1: layer-1 step ----
    F8 a0, a1, a2, a3;
    a0.q = *(const uint4*)&sh1[cur][col][0 * 32 + grp * 8];
    a1.q = *(const uint4*)&sh1[cur][col][1 * 32 + grp * 8];
    a2.q = *(const uint4*)&sh1[cur][col][2 * 32 + grp * 8];
    a3.q = *(const uint4*)&sh1[cur][col][3 * 32 + grp * 8];

    // prefetch next x while mfma runs
    const int tn = (t + 1) & 127;
    xpA = *(const float4*)&xrow[tn * 8];
    xpB = *(const float4*)&xrow[tn * 8 + 4];

    f32x4 acc1[4];
#pragma unroll
    for (int gi = 0; gi < 4; ++gi) {
      f32x4 a = {0.f, 0.f, 0.f, 0.f};
      a = __builtin_amdgcn_mfma_f32_16x16x32_bf16(a0.v, B1[gi][0], a, 0, 0, 0);
      a = __builtin_amdgcn_mfma_f32_16x16x32_bf16(a1.v, B1[gi][1], a, 0, 0, 0);
      a = __builtin_amdgcn_mfma_f32_16x16x32_bf16(a2.v, B1[gi][2], a, 0, 0, 0);
      a = __builtin_amdgcn_mfma_f32_16x16x32_bf16(a3.v, B1[gi][3], a, 0, 0, 0);
      a = __builtin_amdgcn_mfma_f32_16x16x32_bf16(ax.v, Bx[gi], a, 0, 0, 0);
      acc1[gi] = a;
    }
    // nonlinearity; lane owns (h = 16*wid+col, batches 4*grp+r)
    float h1n[4];
#pragma unroll
    for (int r = 0; r < 4; ++r) {
      float ig = sigm(acc1[0][r]);
      float fg = sigm(acc1[1][r]);
      float tg = tanh_fast(acc1[2][r]);
      float og = sigm(acc1[3][r]);
      float cc = fg * c1[r] + ig * tg;
      c1[r] = cc;
      h1n[r] = og * tanh_fast(cc);
    }
#pragma unroll
    for (int r = 0; r < 4; ++r)
      *(unsigned*)&sh1[cur ^ 1][4 * grp + r][2 * (wid * 16 + col)] = split_pack(h1n[r]);

    __syncthreads();  // h1(t) visible in buf cur^1

    // ---- phase 2: layer-2 step (waves 0,1) ----
    if (wid < 2) {
      F8 ha0, ha1, ha2, ha3, g0, g1;
      ha0.q = *(const uint4*)&sh1[cur ^ 1][col][0 * 32 + grp * 8];
      ha1.q = *(const uint4*)&sh1[cur ^ 1][col][1 * 32 + grp * 8];
      ha2.q = *(const uint4*)&sh1[cur ^ 1][col][2 * 32 + grp * 8];
      ha3.q = *(const uint4*)&sh1[cur ^ 1][col][3 * 32 + grp * 8];
      g0.q = *(const uint4*)&sh2[cur][col][0 * 32 + grp * 8];
      g1.q = *(const uint4*)&sh2[cur][col][1 * 32 + grp * 8];

      f32x4 acc2[4];
#pragma unroll
      for (int gi = 0; gi < 4; ++gi) {
        f32x4 a = {bias2[gi], bias2[gi], bias2[gi], bias2[gi]};
        a = __builtin_amdgcn_mfma_f32_16x16x32_bf16(ha0.v, B2a[gi][0], a, 0, 0, 0);
        a = __builtin_amdgcn_mfma_f32_16x16x32_bf16(ha1.v, B2a[gi][1], a, 0, 0, 0);
        a = __builtin_amdgcn_mfma_f32_16x16x32_bf16(ha2.v, B2a[gi][2], a, 0, 0, 0);
        a = __builtin_amdgcn_mfma_f32_16x16x32_bf16(ha3.v, B2a[gi][3], a, 0, 0, 0);
        a = __builtin_amdgcn_mfma_f32_16x16x32_bf16(g0.v, B2b[gi][0], a, 0, 0, 0);
        a = __builtin_amdgcn_mfma_f32_16x16x32_bf16(g1.v, B2b[gi][1], a, 0, 0, 0);
        acc2[gi] = a;
      }
      const float wo = sWo[t * 32 + wid * 16 + col];
      float h2n[4];
#pragma unroll
      for (int r = 0; r < 4; ++r) {
        float ig = sigm(acc2[0][r]);
        float fg = sigm(acc2[1][r]);
        float tg = tanh_fast(acc2[2][r]);
        float og = sigm(acc2[3][r]);
        float cc = fg * c2[r] + ig * tg;
        c2[r] = cc;
        h2n[r] = og * tanh_fast(cc);
        accO[r] += h2n[r] * wo;
      }
#pragma unroll
      for (int r = 0; r < 4; ++r)
        *(unsigned*)&sh2[cur ^ 1][4 * grp + r][2 * (wid * 16 + col)] = split_pack(h2n[r]);
    }
    __syncthreads();  // h2(t) visible; buf swap safe
    cur ^= 1;
  }

  // ---- output reduce: sum over h2 (16 lanes per wave-half), then waves ----
  if (wid < 2) {
#pragma unroll
    for (int off = 1; off < 16; off <<= 1) {
#pragma unroll
      for (int r = 0; r < 4; ++r) accO[r] += __shfl_xor(accO[r], off);
    }
    if (col == 0) {
#pragma unroll
      for (int r = 0; r < 4; ++r) sOut[wid * 16 + 4 * grp + r] = accO[r];
    }
  }
  __syncthreads();
  if (tid < 16) out[b0 + tid] = sOut[tid] + sOut[16 + tid] + bout[0];
}

extern "C" void kernel_launch(void* const* d_in, const int* in_sizes, int n_in,
                              void* d_out, int out_size, void* d_ws, size_t ws_size,
                              hipStream_t stream) {
  const float* x    = (const float*)d_in[0];
  const float* tme  = (const float*)d_in[1];
  const float* Wc   = (const float*)d_in[2];
  const float* bc   = (const float*)d_in[3];
  const float* Wih1 = (const float*)d_in[4];
  const float* Whh1 = (const float*)d_in[5];
  const float* Wih2 = (const float*)d_in[6];
  const float* Whh2 = (const float*)d_in[7];
  const float* bih2 = (const float*)d_in[8];
  const float* bhh2 = (const float*)d_in[9];
  const float* Wout = (const float*)d_in[10];
  const float* bout = (const float*)d_in[11];
  float* outp = (float*)d_out;
  float* x1 = (float*)d_ws;  // [4096][1024] f32 = 16.78 MB

  dim3 gA(8, 32);  // N/128, M/128
  combine_gemm<<<gA, 256, 0, stream>>>(x, tme, Wc, bc, x1);
  lstm_fused_mfma<<<256, 256, 0, stream>>>(x1, Wih1, Whh1, Wih2, Whh2,
                                           bih2, bhh2, Wout, bout, outp);
}

// Round 3
// 339.787 us; speedup vs baseline: 3.9873x; 1.2821x over previous
//
#include <hip/hip_runtime.h>
#include <math.h>

// B=4096, S=128, F=8, H1=64, H2=32
// Stage A: x1p = split_pack(relu(concat(x,time) @ Wc^T + bc))  [4096][1024] u32 -> d_ws
// Stage B: fused LSTM1 || LSTM2(lag-1) -> out projection, MFMA bf16 split-state
//          swapped operands: A = weights (gate-rows), B = state (batch cols)

typedef __bf16 bf16x8 __attribute__((ext_vector_type(8)));
typedef float f32x4 __attribute__((ext_vector_type(4)));

union F8 { uint4 q; unsigned u[4]; bf16x8 v; };

__device__ __forceinline__ float sigm(float x) { return 1.f / (1.f + __expf(-x)); }
__device__ __forceinline__ float tanh_fast(float x) {
  x = fminf(fmaxf(x, -15.f), 15.f);
  float e = __expf(2.f * x);
  return (e - 1.f) / (e + 1.f);
}

// split f32 into bf16 hi (trunc) + bf16 lo (residual), packed lo<<16|hi
__device__ __forceinline__ unsigned split_pack(float x) {
  unsigned u = __float_as_uint(x);
  float hif = __uint_as_float(u & 0xffff0000u);
  float lo = x - hif;
  return (u >> 16) | (__float_as_uint(lo) & 0xffff0000u);
}

// bf16 RNE of w, duplicated into both halves of a u32 (pairs with hi/lo slots)
__device__ __forceinline__ unsigned dup_bf(float w) {
  unsigned u = __float_as_uint(w);
  unsigned b = (u + 0x7fffu + ((u >> 16) & 1u)) >> 16;
  return b | (b << 16);
}

// ---------------- Kernel A: combine GEMM + relu + split-pack ----------------
__global__ __launch_bounds__(256) void combine_gemm(
    const float* __restrict__ x, const float* __restrict__ tme,
    const float* __restrict__ Wc, const float* __restrict__ bc,
    unsigned* __restrict__ x1p)
{
  __shared__ float As[16][132];
  __shared__ float Bs[16][132];
  const int tid = threadIdx.x;
  const int tx = tid & 15, ty = tid >> 4;
  const int M0 = blockIdx.y * 128, N0 = blockIdx.x * 128;
  const int r0 = ty * 8, c0 = tx * 8;
  float acc[8][8];
#pragma unroll
  for (int i = 0; i < 8; ++i)
#pragma unroll
    for (int j = 0; j < 8; ++j) acc[i][j] = 0.f;

  for (int kt = 0; kt < 1024; kt += 16) {
#pragma unroll
    for (int i = 0; i < 8; ++i) {
      int idx = tid + i * 256;
      int r = idx >> 4, kk = idx & 15;
      As[kk][r] = x[(size_t)(M0 + r) * 1024 + kt + kk];
      Bs[kk][r] = Wc[(size_t)(N0 + r) * 1025 + kt + kk];
    }
    __syncthreads();
#pragma unroll
    for (int kk = 0; kk < 16; ++kk) {
      float4 a0 = *(const float4*)&As[kk][r0];
      float4 a1 = *(const float4*)&As[kk][r0 + 4];
      float4 b0 = *(const float4*)&Bs[kk][c0];
      float4 b1 = *(const float4*)&Bs[kk][c0 + 4];
      float av[8] = {a0.x, a0.y, a0.z, a0.w, a1.x, a1.y, a1.z, a1.w};
      float bv[8] = {b0.x, b0.y, b0.z, b0.w, b1.x, b1.y, b1.z, b1.w};
#pragma unroll
      for (int i = 0; i < 8; ++i)
#pragma unroll
        for (int j = 0; j < 8; ++j)
          acc[i][j] += av[i] * bv[j];
    }
    __syncthreads();
  }

  float wlast[8], bcv[8];
#pragma unroll
  for (int j = 0; j < 8; ++j) {
    int o = N0 + c0 + j;
    wlast[j] = Wc[(size_t)o * 1025 + 1024];
    bcv[j] = bc[o];
  }
#pragma unroll
  for (int i = 0; i < 8; ++i) {
    int b = M0 + r0 + i;
    float tv = tme[b];
    unsigned p8[8];
#pragma unroll
    for (int j = 0; j < 8; ++j)
      p8[j] = split_pack(fmaxf(acc[i][j] + tv * wlast[j] + bcv[j], 0.f));
    uint4 s0 = {p8[0], p8[1], p8[2], p8[3]};
    uint4 s1 = {p8[4], p8[5], p8[6], p8[7]};
    *(uint4*)&x1p[(size_t)b * 1024 + N0 + c0] = s0;
    *(uint4*)&x1p[(size_t)b * 1024 + N0 + c0 + 4] = s1;
  }
}

// ---------------- Kernel B: fused LSTM, balanced + lag-1 L2 -----------------
#define ROW1 168  // shorts per sh1 row: 128 h1-slots + 16 x-slots + 16 zero + pad
#define ROW2 72   // shorts per sh2 row: 64 h2-slots + pad

__global__ __launch_bounds__(256, 1) void lstm_fused_mfma(
    const unsigned* __restrict__ x1p,
    const float* __restrict__ Wih1, const float* __restrict__ Whh1,
    const float* __restrict__ Wih2, const float* __restrict__ Whh2,
    const float* __restrict__ bih2, const float* __restrict__ bhh2,
    const float* __restrict__ Wout, const float* __restrict__ bout,
    float* __restrict__ out)
{
  __shared__ float sWo[4096];
  __shared__ __align__(16) unsigned short sh1[2][16][ROW1];
  __shared__ __align__(16) unsigned short sh2[2][16][ROW2];
  __shared__ float sOut[4][16];

  const int tid = threadIdx.x;
  const int lane = tid & 63;
  const int w = tid >> 6;      // wave 0..3
  const int col = lane & 15;   // A-row at pack time / B-col (batch) at run time
  const int grp = lane >> 4;   // k-slot group; C rows 4*grp+r
  const int b0 = blockIdx.x * 16;

  // ---- pack A-side weight fragments (once) ----
  // A-frag: lane holds A[row = lane&15][slots grp*8 .. +7]; slot pair (2j,2j+1)
  // inside a chunk <-> k = chunk*16 + grp*4 + j, weight dup'd for hi/lo.
  const int m1 = col >> 2, g1 = col & 3;  // A row = 4*m + gate
  bf16x8 A1[4][5];  // L1: tile j, chunks 0-3 = h1 (k=64), chunk 4 = x (8 dims)
#pragma unroll
  for (int j = 0; j < 4; ++j) {
    const int h1r = w * 16 + 4 * m1 + j;
    const int wr = g1 * 64 + h1r;
#pragma unroll
    for (int c = 0; c < 5; ++c) {
      F8 f;
#pragma unroll
      for (int jj = 0; jj < 4; ++jj) {
        float wv;
        if (c < 4) wv = Whh1[wr * 64 + c * 16 + grp * 4 + jj];
        else { int d = grp * 4 + jj; wv = (d < 8) ? Wih1[wr * 8 + d] : 0.f; }
        f.u[jj] = dup_bf(wv);
      }
      A1[j][c] = f.v;
    }
  }
  bf16x8 A2[2][6];  // L2: tiles i (u=2w+i), chunks 0-3 = h1, 4-5 = h2
  float bias2[2][4];
  int h2o[2];
#pragma unroll
  for (int i = 0; i < 2; ++i) {
    const int u = 2 * w + i;
    const int h2r = 4 * u + m1;
    const int wr = g1 * 32 + h2r;
#pragma unroll
    for (int c = 0; c < 6; ++c) {
      F8 f;
#pragma unroll
      for (int jj = 0; jj < 4; ++jj) {
        float wv = (c < 4) ? Wih2[wr * 64 + c * 16 + grp * 4 + jj]
                           : Whh2[wr * 32 + (c - 4) * 16 + grp * 4 + jj];
        f.u[jj] = dup_bf(wv);
      }
      A2[i][c] = f.v;
    }
    h2o[i] = 4 * u + grp;  // h2 of this lane's cells (C rows 4*grp+r = gates)
#pragma unroll
    for (int r = 0; r < 4; ++r)
      bias2[i][r] = bih2[r * 32 + h2o[i]] + bhh2[r * 32 + h2o[i]];
  }

  // ---- LDS init: Wout stage + zero state (h1(-1)=h2(-1)=0, zero pad slots) ----
  for (int i2 = tid; i2 < 4096; i2 += 256) sWo[i2] = Wout[i2];
  {
    unsigned short* z = &sh1[0][0][0];
    for (int i2 = tid; i2 < 2 * 16 * ROW1; i2 += 256) z[i2] = 0;
    unsigned short* z2 = &sh2[0][0][0];
    for (int i2 = tid; i2 < 2 * 16 * ROW2; i2 += 256) z2[i2] = 0;
  }
  __syncthreads();
  // stage x(0) into sh1[0] x-slots
  const int xb = tid >> 3, xd = tid & 7;
  const unsigned* xsrc = x1p + (size_t)(b0 + xb) * 1024;
  if (tid < 128) *(unsigned*)&sh1[0][xb][128 + 2 * xd] = xsrc[xd];
  __syncthreads();

  float c1[4] = {0.f, 0.f, 0.f, 0.f};
  float c2[2] = {0.f, 0.f};
  float accO = 0.f;
  int cur = 0;

  for (int t = 0; t <= 128; ++t) {  // 129 phases: L1 for t<128, L2(t-1) for t>0
    const bool doL1 = (t < 128);
    const bool doL2 = (t > 0);

    unsigned xv = 0;
    if (doL1 && tid < 128) xv = xsrc[((t + 1) & 127) * 8 + xd];  // prefetch x(t+1)

    // B-frags (state), shared by L1 and L2 tiles
    F8 s1f[5], s2f[2];
#pragma unroll
    for (int c = 0; c < 5; ++c)
      s1f[c].q = *(const uint4*)&sh1[cur][col][c * 32 + grp * 8];
#pragma unroll
    for (int c = 0; c < 2; ++c)
      s2f[c].q = *(const uint4*)&sh2[cur][col][c * 32 + grp * 8];

    if (doL1) {
      f32x4 acc[4];
#pragma unroll
      for (int j = 0; j < 4; ++j) {
        f32x4 a = {0.f, 0.f, 0.f, 0.f};
#pragma unroll
        for (int c = 0; c < 5; ++c)
          a = __builtin_amdgcn_mfma_f32_16x16x32_bf16(A1[j][c], s1f[c].v, a, 0, 0, 0);
        acc[j] = a;
      }
      unsigned hp[4];
#pragma unroll
      for (int j = 0; j < 4; ++j) {  // cell (b=col, h1=w*16+4*grp+j), gates = regs
        float ig = sigm(acc[j][0]);
        float fg = sigm(acc[j][1]);
        float tg = tanh_fast(acc[j][2]);
        float og = sigm(acc[j][3]);
        float cc = fg * c1[j] + ig * tg;
        c1[j] = cc;
        hp[j] = split_pack(og * tanh_fast(cc));
      }
      uint4 hw = {hp[0], hp[1], hp[2], hp[3]};
      *(uint4*)&sh1[cur ^ 1][col][2 * (w * 16 + 4 * grp)] = hw;
    }

    if (doL2) {
      const int tp = t - 1;
#pragma unroll
      for (int i = 0; i < 2; ++i) {
        f32x4 a = {bias2[i][0], bias2[i][1], bias2[i][2], bias2[i][3]};
#pragma unroll
        for (int c = 0; c < 4; ++c)
          a = __builtin_amdgcn_mfma_f32_16x16x32_bf16(A2[i][c], s1f[c].v, a, 0, 0, 0);
#pragma unroll
        for (int c = 0; c < 2; ++c)
          a = __builtin_amdgcn_mfma_f32_16x16x32_bf16(A2[i][4 + c], s2f[c].v, a, 0, 0, 0);
        float ig = sigm(a[0]);
        float fg = sigm(a[1]);
        float tg = tanh_fast(a[2]);
        float og = sigm(a[3]);
        float cc = fg * c2[i] + ig * tg;
        c2[i] = cc;
        float hn = og * tanh_fast(cc);
        accO += hn * sWo[tp * 32 + h2o[i]];
        *(unsigned*)&sh2[cur ^ 1][col][2 * h2o[i]] = split_pack(hn);
      }
    }

    if (doL1 && tid < 128)
      *(unsigned*)&sh1[cur ^ 1][xb][128 + 2 * xd] = xv;  // x(t+1) for next phase

    __syncthreads();
    cur ^= 1;
  }

  // ---- output reduce: over grp (lanes 16/32 apart) then waves ----
  accO += __shfl_xor(accO, 16);
  accO += __shfl_xor(accO, 32);
  if (grp == 0) sOut[w][col] = accO;
  __syncthreads();
  if (tid < 16)
    out[b0 + tid] = sOut[0][tid] + sOut[1][tid] + sOut[2][tid] + sOut[3][tid] + bout[0];
}

extern "C" void kernel_launch(void* const* d_in, const int* in_sizes, int n_in,
                              void* d_out, int out_size, void* d_ws, size_t ws_size,
                              hipStream_t stream) {
  const float* x    = (const float*)d_in[0];
  const float* tme  = (const float*)d_in[1];
  const float* Wc   = (const float*)d_in[2];
  const float* bc   = (const float*)d_in[3];
  const float* Wih1 = (const float*)d_in[4];
  const float* Whh1 = (const float*)d_in[5];
  const float* Wih2 = (const float*)d_in[6];
  const float* Whh2 = (const float*)d_in[7];
  const float* bih2 = (const float*)d_in[8];
  const float* bhh2 = (const float*)d_in[9];
  const float* Wout = (const float*)d_in[10];
  const float* bout = (const float*)d_in[11];
  float* outp = (float*)d_out;
  unsigned* x1p = (unsigned*)d_ws;  // [4096][1024] packed split-bf16 = 16.78 MB

  dim3 gA(8, 32);  // N/128, M/128
  combine_gemm<<<gA, 256, 0, stream>>>(x, tme, Wc, bc, x1p);
  lstm_fused_mfma<<<256, 256, 0, stream>>>(x1p, Wih1, Whh1, Wih2, Whh2,
                                           bih2, bhh2, Wout, bout, outp);
}

// Round 4
// 323.214 us; speedup vs baseline: 4.1917x; 1.0513x over previous
//
#include <hip/hip_runtime.h>
#include <math.h>

// B=4096, S=128, F=8, H1=64, H2=32
// Stage A: x1p = split_pack(relu(concat(x,time) @ Wc^T + bc))  [4096][1024] u32 -> d_ws
// Stage B: fused LSTM1 || LSTM2(lag-1) -> out projection, MFMA bf16 split-state
//          512 threads (2 waves/SIMD), x fully LDS-resident, weights in VGPRs.

typedef __bf16 bf16x8 __attribute__((ext_vector_type(8)));
typedef float f32x4 __attribute__((ext_vector_type(4)));

union F8 { uint4 q; unsigned u[4]; bf16x8 v; };

__device__ __forceinline__ float sigm(float x) { return 1.f / (1.f + __expf(-x)); }
__device__ __forceinline__ float tanh_fast(float x) {
  x = fminf(fmaxf(x, -15.f), 15.f);
  float e = __expf(2.f * x);
  return (e - 1.f) / (e + 1.f);
}

// split f32 into bf16 hi (trunc) + bf16 lo (trunc residual), packed lo<<16|hi
__device__ __forceinline__ unsigned split_pack(float x) {
  unsigned u = __float_as_uint(x);
  float hif = __uint_as_float(u & 0xffff0000u);
  float lo = x - hif;
  return (u >> 16) | (__float_as_uint(lo) & 0xffff0000u);
}

// bf16 RNE of w, duplicated into both halves of a u32 (pairs with hi/lo slots)
__device__ __forceinline__ unsigned dup_bf(float w) {
  unsigned u = __float_as_uint(w);
  unsigned b = (u + 0x7fffu + ((u >> 16) & 1u)) >> 16;
  return b | (b << 16);
}

// ---------------- Kernel A: combine GEMM + relu + split-pack ----------------
__global__ __launch_bounds__(256) void combine_gemm(
    const float* __restrict__ x, const float* __restrict__ tme,
    const float* __restrict__ Wc, const float* __restrict__ bc,
    unsigned* __restrict__ x1p)
{
  __shared__ float As[16][132];
  __shared__ float Bs[16][132];
  const int tid = threadIdx.x;
  const int tx = tid & 15, ty = tid >> 4;
  const int M0 = blockIdx.y * 128, N0 = blockIdx.x * 128;
  const int r0 = ty * 8, c0 = tx * 8;
  float acc[8][8];
#pragma unroll
  for (int i = 0; i < 8; ++i)
#pragma unroll
    for (int j = 0; j < 8; ++j) acc[i][j] = 0.f;

  for (int kt = 0; kt < 1024; kt += 16) {
#pragma unroll
    for (int i = 0; i < 8; ++i) {
      int idx = tid + i * 256;
      int r = idx >> 4, kk = idx & 15;
      As[kk][r] = x[(size_t)(M0 + r) * 1024 + kt + kk];
      Bs[kk][r] = Wc[(size_t)(N0 + r) * 1025 + kt + kk];
    }
    __syncthreads();
#pragma unroll
    for (int kk = 0; kk < 16; ++kk) {
      float4 a0 = *(const float4*)&As[kk][r0];
      float4 a1 = *(const float4*)&As[kk][r0 + 4];
      float4 b0 = *(const float4*)&Bs[kk][c0];
      float4 b1 = *(const float4*)&Bs[kk][c0 + 4];
      float av[8] = {a0.x, a0.y, a0.z, a0.w, a1.x, a1.y, a1.z, a1.w};
      float bv[8] = {b0.x, b0.y, b0.z, b0.w, b1.x, b1.y, b1.z, b1.w};
#pragma unroll
      for (int i = 0; i < 8; ++i)
#pragma unroll
        for (int j = 0; j < 8; ++j)
          acc[i][j] += av[i] * bv[j];
    }
    __syncthreads();
  }

  float wlast[8], bcv[8];
#pragma unroll
  for (int j = 0; j < 8; ++j) {
    int o = N0 + c0 + j;
    wlast[j] = Wc[(size_t)o * 1025 + 1024];
    bcv[j] = bc[o];
  }
#pragma unroll
  for (int i = 0; i < 8; ++i) {
    int b = M0 + r0 + i;
    float tv = tme[b];
    unsigned p8[8];
#pragma unroll
    for (int j = 0; j < 8; ++j)
      p8[j] = split_pack(fmaxf(acc[i][j] + tv * wlast[j] + bcv[j], 0.f));
    uint4 s0 = {p8[0], p8[1], p8[2], p8[3]};
    uint4 s1 = {p8[4], p8[5], p8[6], p8[7]};
    *(uint4*)&x1p[(size_t)b * 1024 + N0 + c0] = s0;
    *(uint4*)&x1p[(size_t)b * 1024 + N0 + c0 + 4] = s1;
  }
}

// ---------------- Kernel B: fused LSTM, 8 waves, lag-1 L2 -------------------
// wave w: vw = w>>1 (batch-group role), wsub = w&1.
// L1: 2 tiles j = 2*wsub+{0,1}, h1 = vw*16 + 4*grp + j.
// L2: 1 tile u = 2*vw + wsub,   h2 = 4*u + grp.
#define ROW1 136  // shorts per sh1 row: 128 h1-slots + 8 pad
#define ROW2 72   // shorts per sh2 row: 64 h2-slots + 8 pad

__global__ __launch_bounds__(512, 2) void lstm_fused_mfma(
    const unsigned* __restrict__ x1p,
    const float* __restrict__ Wih1, const float* __restrict__ Whh1,
    const float* __restrict__ Wih2, const float* __restrict__ Whh2,
    const float* __restrict__ bih2, const float* __restrict__ bhh2,
    const float* __restrict__ Wout, const float* __restrict__ bout,
    float* __restrict__ out)
{
  extern __shared__ __align__(16) char smraw[];
  unsigned* sxw = (unsigned*)smraw;                                  // [128][16][8] u32, 64KB
  float* sWo = (float*)(smraw + 65536);                              // [4096], 16KB
  unsigned short (*sh1)[16][ROW1] =
      (unsigned short (*)[16][ROW1])(smraw + 65536 + 16384);         // [2][16][136], 8704B
  unsigned short (*sh2)[16][ROW2] =
      (unsigned short (*)[16][ROW2])(smraw + 65536 + 16384 + 8704);  // [2][16][72], 4608B
  float (*sOut)[16] = (float (*)[16])(smraw + 65536 + 16384 + 8704 + 4608);  // [8][16]

  const int tid = threadIdx.x;
  const int lane = tid & 63;
  const int w = tid >> 6;       // wave 0..7
  const int vw = w >> 1;        // virtual wave 0..3
  const int wsub = w & 1;
  const int col = lane & 15;    // A-row at pack time / B-col (batch) at run time
  const int grp = lane >> 4;    // k-slot group; C rows 4*grp+r
  const int b0 = blockIdx.x * 16;

  // ---- pack A-side weight fragments (once) ----
  // lane holds A[row = col][k-slots grp*4+{0..3}] per 32-k chunk, dup'd hi/lo.
  const int m1 = col >> 2, g1 = col & 3;  // A row = 4*m + gate
  bf16x8 A1[2][5];  // L1 tiles jj: chunks 0-3 = h1 (k=64), chunk 4 = x (8 dims)
#pragma unroll
  for (int jj = 0; jj < 2; ++jj) {
    const int j = 2 * wsub + jj;
    const int wr = g1 * 64 + vw * 16 + 4 * m1 + j;
#pragma unroll
    for (int c = 0; c < 5; ++c) {
      F8 f;
#pragma unroll
      for (int q = 0; q < 4; ++q) {
        float wv;
        if (c < 4) wv = Whh1[wr * 64 + c * 16 + grp * 4 + q];
        else { int d = grp * 4 + q; wv = (d < 8) ? Wih1[wr * 8 + d] : 0.f; }
        f.u[q] = dup_bf(wv);
      }
      A1[jj][c] = f.v;
    }
  }
  bf16x8 A2[6];  // L2 tile: chunks 0-3 = h1, 4-5 = h2
  const int u = 2 * vw + wsub;
  {
    const int wr = g1 * 32 + 4 * u + m1;
#pragma unroll
    for (int c = 0; c < 6; ++c) {
      F8 f;
#pragma unroll
      for (int q = 0; q < 4; ++q) {
        float wv = (c < 4) ? Wih2[wr * 64 + c * 16 + grp * 4 + q]
                           : Whh2[wr * 32 + (c - 4) * 16 + grp * 4 + q];
        f.u[q] = dup_bf(wv);
      }
      A2[c] = f.v;
    }
  }
  const int h2o = 4 * u + grp;  // this lane's L2 cell (C rows = gates)
  float bias2[4];
#pragma unroll
  for (int r = 0; r < 4; ++r)
    bias2[r] = bih2[r * 32 + h2o] + bhh2[r * 32 + h2o];

  // ---- LDS init ----
  for (int i2 = tid; i2 < 4096; i2 += 512) sWo[i2] = Wout[i2];
  {
    unsigned short* z = &sh1[0][0][0];
    for (int i2 = tid; i2 < 2 * 16 * ROW1; i2 += 512) z[i2] = 0;
    unsigned short* z2 = &sh2[0][0][0];
    for (int i2 = tid; i2 < 2 * 16 * ROW2; i2 += 512) z2[i2] = 0;
  }
  // preload ALL x for this block: [t][batch][8] u32, coalesced on source
  for (int idx = tid; idx < 16 * 128 * 8; idx += 512) {
    int bb = idx >> 10, rem = idx & 1023;
    int t = rem >> 3, d = rem & 7;
    sxw[t * 128 + bb * 8 + d] = x1p[(size_t)(b0 + bb) * 1024 + rem];
  }
  __syncthreads();

  float c1[2] = {0.f, 0.f};
  float c2 = 0.f;
  float accO = 0.f;
  int cur = 0;

  for (int t = 0; t <= 128; ++t) {  // phase t: L1(t) for t<128, L2(t-1) for t>0
    const bool doL1 = (t < 128);
    const bool doL2 = (t > 0);

    F8 s1f[5], s2f[2];
#pragma unroll
    for (int c = 0; c < 4; ++c)
      s1f[c].q = *(const uint4*)&sh1[cur][col][c * 32 + grp * 8];
#pragma unroll
    for (int c = 0; c < 2; ++c)
      s2f[c].q = *(const uint4*)&sh2[cur][col][c * 32 + grp * 8];
    if (doL1)
      s1f[4].q = *(const uint4*)&sxw[t * 128 + col * 8 + (grp & 1) * 4];

    if (doL1) {
      f32x4 acc[2];
#pragma unroll
      for (int jj = 0; jj < 2; ++jj) {
        f32x4 a = {0.f, 0.f, 0.f, 0.f};
#pragma unroll
        for (int c = 0; c < 5; ++c)
          a = __builtin_amdgcn_mfma_f32_16x16x32_bf16(A1[jj][c], s1f[c].v, a, 0, 0, 0);
        acc[jj] = a;
      }
      unsigned hp[2];
#pragma unroll
      for (int jj = 0; jj < 2; ++jj) {  // cell (b=col, h1 = vw*16+4*grp+2*wsub+jj)
        float ig = sigm(acc[jj][0]);
        float fg = sigm(acc[jj][1]);
        float tg = tanh_fast(acc[jj][2]);
        float og = sigm(acc[jj][3]);
        float cc = fg * c1[jj] + ig * tg;
        c1[jj] = cc;
        hp[jj] = split_pack(og * tanh_fast(cc));
      }
      uint2 hw = {hp[0], hp[1]};
      *(uint2*)&sh1[cur ^ 1][col][2 * (vw * 16 + 4 * grp + 2 * wsub)] = hw;
    }

    if (doL2) {
      f32x4 a = {bias2[0], bias2[1], bias2[2], bias2[3]};
#pragma unroll
      for (int c = 0; c < 4; ++c)
        a = __builtin_amdgcn_mfma_f32_16x16x32_bf16(A2[c], s1f[c].v, a, 0, 0, 0);
#pragma unroll
      for (int c = 0; c < 2; ++c)
        a = __builtin_amdgcn_mfma_f32_16x16x32_bf16(A2[4 + c], s2f[c].v, a, 0, 0, 0);
      float ig = sigm(a[0]);
      float fg = sigm(a[1]);
      float tg = tanh_fast(a[2]);
      float og = sigm(a[3]);
      float cc = fg * c2 + ig * tg;
      c2 = cc;
      float hn = og * tanh_fast(cc);
      accO += hn * sWo[(t - 1) * 32 + h2o];
      *(unsigned*)&sh2[cur ^ 1][col][2 * h2o] = split_pack(hn);
    }

    __syncthreads();
    cur ^= 1;
  }

  // ---- output reduce: over grp (lanes 16/32 apart) then 8 waves ----
  accO += __shfl_xor(accO, 16);
  accO += __shfl_xor(accO, 32);
  if (grp == 0) sOut[w][col] = accO;
  __syncthreads();
  if (tid < 16) {
    float s = bout[0];
#pragma unroll
    for (int ww = 0; ww < 8; ++ww) s += sOut[ww][tid];
    out[b0 + tid] = s;
  }
}

extern "C" void kernel_launch(void* const* d_in, const int* in_sizes, int n_in,
                              void* d_out, int out_size, void* d_ws, size_t ws_size,
                              hipStream_t stream) {
  const float* x    = (const float*)d_in[0];
  const float* tme  = (const float*)d_in[1];
  const float* Wc   = (const float*)d_in[2];
  const float* bc   = (const float*)d_in[3];
  const float* Wih1 = (const float*)d_in[4];
  const float* Whh1 = (const float*)d_in[5];
  const float* Wih2 = (const float*)d_in[6];
  const float* Whh2 = (const float*)d_in[7];
  const float* bih2 = (const float*)d_in[8];
  const float* bhh2 = (const float*)d_in[9];
  const float* Wout = (const float*)d_in[10];
  const float* bout = (const float*)d_in[11];
  float* outp = (float*)d_out;
  unsigned* x1p = (unsigned*)d_ws;  // [4096][1024] packed split-bf16 = 16.78 MB

  dim3 gA(8, 32);  // N/128, M/128
  combine_gemm<<<gA, 256, 0, stream>>>(x, tme, Wc, bc, x1p);

  const size_t smem = 65536 + 16384 + 8704 + 4608 + 8 * 16 * sizeof(float);
  hipFuncSetAttribute(reinterpret_cast<const void*>(lstm_fused_mfma),
                      hipFuncAttributeMaxDynamicSharedMemorySize, (int)smem);
  lstm_fused_mfma<<<256, 512, smem, stream>>>(x1p, Wih1, Whh1, Wih2, Whh2,
                                              bih2, bhh2, Wout, bout, outp);
}

// Round 5
// 144.281 us; speedup vs baseline: 9.3901x; 2.2402x over previous
//
#include <hip/hip_runtime.h>
#include <math.h>

// B=4096, S=128, F=8, H1=64, H2=32
// Stage A: x1p = split_pack(relu(concat(x,time) @ Wc^T + bc)) via split-bf16 MFMA
// Stage B: fused LSTM1 || LSTM2(lag-1) -> out projection, MFMA bf16 split-state

typedef __bf16 bf16x8 __attribute__((ext_vector_type(8)));
typedef float f32x4 __attribute__((ext_vector_type(4)));

union F8 { uint4 q; unsigned u[4]; bf16x8 v; };

// fast activations: v_exp_f32 + v_rcp_f32 (saturate cleanly at extremes)
__device__ __forceinline__ float sigm(float x) {
  return __builtin_amdgcn_rcpf(1.f + __builtin_amdgcn_exp2f(x * -1.44269504f));
}
__device__ __forceinline__ float tanh_fast(float x) {
  return 1.f - 2.f * __builtin_amdgcn_rcpf(1.f + __builtin_amdgcn_exp2f(x * 2.88539008f));
}

// split f32 into bf16 hi (trunc) + bf16 lo (trunc residual), packed lo<<16|hi
__device__ __forceinline__ unsigned split_pack(float x) {
  unsigned u = __float_as_uint(x);
  float hif = __uint_as_float(u & 0xffff0000u);
  float lo = x - hif;
  return (u >> 16) | (__float_as_uint(lo) & 0xffff0000u);
}

// bf16 RNE of w, duplicated into both halves of a u32 (pairs with hi/lo slots)
__device__ __forceinline__ unsigned dup_bf(float w) {
  unsigned u = __float_as_uint(w);
  unsigned b = (u + 0x7fffu + ((u >> 16) & 1u)) >> 16;
  return b | (b << 16);
}

// ---------------- Kernel A: combine GEMM via split-bf16 MFMA ----------------
// M=4096(batch) x N=1024(out) x K=1024, + time column + bias + relu + pack.
// 3-product split: Wh*xh + Wh*xl + Wl*xh  (~f32 accuracy).
// Grid (16,32)=512 blocks (2/CU), 256 thr (4 waves); BM=128 BN=64 BK=32.
#define CB_PAD 40  // shorts per staged row (32 + 8): 80B, 16B-aligned rows

__global__ __launch_bounds__(256, 2) void combine_mfma(
    const float* __restrict__ x, const float* __restrict__ tme,
    const float* __restrict__ Wc, const float* __restrict__ bc,
    unsigned* __restrict__ x1p)
{
  __shared__ __align__(16) char smem[128 * 68 * 4];  // 34816 B, overlaid
  unsigned short (*sAh)[CB_PAD] = (unsigned short (*)[CB_PAD])(smem);
  unsigned short (*sAl)[CB_PAD] = (unsigned short (*)[CB_PAD])(smem + 10240);
  unsigned short (*sBh)[CB_PAD] = (unsigned short (*)[CB_PAD])(smem + 20480);
  unsigned short (*sBl)[CB_PAD] = (unsigned short (*)[CB_PAD])(smem + 25600);
  unsigned (*Cst)[68] = (unsigned (*)[68])smem;      // epilogue reuse
  __shared__ float sT[128];
  __shared__ float sWl[64];
  __shared__ float sBc[64];

  const int tid = threadIdx.x;
  const int lane = tid & 63;
  const int w = tid >> 6;
  const int r = lane & 15, grp = lane >> 4;
  const int M0 = blockIdx.y * 128, N0 = blockIdx.x * 64;

  if (tid < 128) sT[tid] = tme[M0 + tid];
  else if (tid < 192) sWl[tid - 128] = Wc[(size_t)(N0 + tid - 128) * 1025 + 1024];
  else sBc[tid - 192] = bc[N0 + tid - 192];

  f32x4 acc[2][4];
#pragma unroll
  for (int i = 0; i < 2; ++i)
#pragma unroll
    for (int j = 0; j < 4; ++j) acc[i][j] = f32x4{0.f, 0.f, 0.f, 0.f};

  for (int kt = 0; kt < 1024; kt += 32) {
    // stage A (x): 128 rows x 32k; 1024 float4, 4/thread
#pragma unroll
    for (int i = 0; i < 4; ++i) {
      int idx = tid + i * 256;
      int row = idx >> 3, kq = idx & 7;
      float4 v = *(const float4*)&x[(size_t)(M0 + row) * 1024 + kt + kq * 4];
      unsigned u0 = __float_as_uint(v.x), u1 = __float_as_uint(v.y);
      unsigned u2 = __float_as_uint(v.z), u3 = __float_as_uint(v.w);
      uint2 hw = {(u0 >> 16) | (u1 & 0xffff0000u), (u2 >> 16) | (u3 & 0xffff0000u)};
      float l0 = v.x - __uint_as_float(u0 & 0xffff0000u);
      float l1 = v.y - __uint_as_float(u1 & 0xffff0000u);
      float l2 = v.z - __uint_as_float(u2 & 0xffff0000u);
      float l3 = v.w - __uint_as_float(u3 & 0xffff0000u);
      uint2 lw = {(__float_as_uint(l0) >> 16) | (__float_as_uint(l1) & 0xffff0000u),
                  (__float_as_uint(l2) >> 16) | (__float_as_uint(l3) & 0xffff0000u)};
      *(uint2*)&sAh[row][kq * 4] = hw;
      *(uint2*)&sAl[row][kq * 4] = lw;
    }
    // stage B (Wc): 64 rows x 32k; 512 float4, 2/thread
#pragma unroll
    for (int i = 0; i < 2; ++i) {
      int idx = tid + i * 256;
      int row = idx >> 3, kq = idx & 7;
      float4 v = *(const float4*)&Wc[(size_t)(N0 + row) * 1025 + kt + kq * 4];
      unsigned u0 = __float_as_uint(v.x), u1 = __float_as_uint(v.y);
      unsigned u2 = __float_as_uint(v.z), u3 = __float_as_uint(v.w);
      uint2 hw = {(u0 >> 16) | (u1 & 0xffff0000u), (u2 >> 16) | (u3 & 0xffff0000u)};
      float l0 = v.x - __uint_as_float(u0 & 0xffff0000u);
      float l1 = v.y - __uint_as_float(u1 & 0xffff0000u);
      float l2 = v.z - __uint_as_float(u2 & 0xffff0000u);
      float l3 = v.w - __uint_as_float(u3 & 0xffff0000u);
      uint2 lw = {(__float_as_uint(l0) >> 16) | (__float_as_uint(l1) & 0xffff0000u),
                  (__float_as_uint(l2) >> 16) | (__float_as_uint(l3) & 0xffff0000u)};
      *(uint2*)&sBh[row][kq * 4] = hw;
      *(uint2*)&sBl[row][kq * 4] = lw;
    }
    __syncthreads();

    F8 ah[2], al[2], bh[4], bl[4];
#pragma unroll
    for (int i = 0; i < 2; ++i) {
      ah[i].q = *(const uint4*)&sAh[w * 32 + i * 16 + r][grp * 8];
      al[i].q = *(const uint4*)&sAl[w * 32 + i * 16 + r][grp * 8];
    }
#pragma unroll
    for (int j = 0; j < 4; ++j) {
      bh[j].q = *(const uint4*)&sBh[j * 16 + r][grp * 8];
      bl[j].q = *(const uint4*)&sBl[j * 16 + r][grp * 8];
    }
#pragma unroll
    for (int i = 0; i < 2; ++i)
#pragma unroll
      for (int j = 0; j < 4; ++j) {
        acc[i][j] = __builtin_amdgcn_mfma_f32_16x16x32_bf16(ah[i].v, bh[j].v, acc[i][j], 0, 0, 0);
        acc[i][j] = __builtin_amdgcn_mfma_f32_16x16x32_bf16(ah[i].v, bl[j].v, acc[i][j], 0, 0, 0);
        acc[i][j] = __builtin_amdgcn_mfma_f32_16x16x32_bf16(al[i].v, bh[j].v, acc[i][j], 0, 0, 0);
      }
    __syncthreads();
  }

  // epilogue: time col + bias + relu + pack -> Cst (LDS) -> coalesced store
#pragma unroll
  for (int i = 0; i < 2; ++i) {
#pragma unroll
    for (int j = 0; j < 4; ++j) {
      int n = j * 16 + r;
      float wl = sWl[n], bv = sBc[n];
#pragma unroll
      for (int q = 0; q < 4; ++q) {
        int mm = w * 32 + i * 16 + 4 * grp + q;
        float v = acc[i][j][q] + sT[mm] * wl + bv;
        Cst[mm][n] = split_pack(fmaxf(v, 0.f));
      }
    }
  }
  __syncthreads();
#pragma unroll
  for (int i = 0; i < 8; ++i) {
    int idx = tid + i * 256;
    int row = idx >> 4, c4 = idx & 15;
    uint4 v = *(const uint4*)&Cst[row][c4 * 4];
    *(uint4*)&x1p[(size_t)(M0 + row) * 1024 + N0 + c4 * 4] = v;
  }
}

// ---------------- Kernel B: fused LSTM, 8 waves, lag-1 L2 -------------------
#define ROW1 136  // shorts per sh1 row: 128 h1-slots + 8 pad
#define ROW2 72   // shorts per sh2 row: 64 h2-slots + 8 pad

__global__ __launch_bounds__(512, 2) void lstm_fused_mfma(
    const unsigned* __restrict__ x1p,
    const float* __restrict__ Wih1, const float* __restrict__ Whh1,
    const float* __restrict__ Wih2, const float* __restrict__ Whh2,
    const float* __restrict__ bih2, const float* __restrict__ bhh2,
    const float* __restrict__ Wout, const float* __restrict__ bout,
    float* __restrict__ out)
{
  extern __shared__ __align__(16) char smraw[];
  unsigned* sxw = (unsigned*)smraw;                                  // [128][16][8] u32, 64KB
  float* sWo = (float*)(smraw + 65536);                              // [4096], 16KB
  unsigned short (*sh1)[16][ROW1] =
      (unsigned short (*)[16][ROW1])(smraw + 65536 + 16384);         // [2][16][136]
  unsigned short (*sh2)[16][ROW2] =
      (unsigned short (*)[16][ROW2])(smraw + 65536 + 16384 + 8704);  // [2][16][72]
  float (*sOut)[16] = (float (*)[16])(smraw + 65536 + 16384 + 8704 + 4608);

  const int tid = threadIdx.x;
  const int lane = tid & 63;
  const int w = tid >> 6;       // wave 0..7
  const int vw = w >> 1;        // virtual wave 0..3
  const int wsub = w & 1;
  const int col = lane & 15;    // A-row at pack time / B-col (batch) at run time
  const int grp = lane >> 4;    // k-slot group; C rows 4*grp+r
  const int b0 = blockIdx.x * 16;

  // ---- pack A-side weight fragments (once) ----
  const int m1 = col >> 2, g1 = col & 3;  // A row = 4*m + gate
  bf16x8 A1[2][5];
#pragma unroll
  for (int jj = 0; jj < 2; ++jj) {
    const int j = 2 * wsub + jj;
    const int wr = g1 * 64 + vw * 16 + 4 * m1 + j;
#pragma unroll
    for (int c = 0; c < 5; ++c) {
      F8 f;
#pragma unroll
      for (int q = 0; q < 4; ++q) {
        float wv;
        if (c < 4) wv = Whh1[wr * 64 + c * 16 + grp * 4 + q];
        else { int d = grp * 4 + q; wv = (d < 8) ? Wih1[wr * 8 + d] : 0.f; }
        f.u[q] = dup_bf(wv);
      }
      A1[jj][c] = f.v;
    }
  }
  bf16x8 A2[6];
  const int u = 2 * vw + wsub;
  {
    const int wr = g1 * 32 + 4 * u + m1;
#pragma unroll
    for (int c = 0; c < 6; ++c) {
      F8 f;
#pragma unroll
      for (int q = 0; q < 4; ++q) {
        float wv = (c < 4) ? Wih2[wr * 64 + c * 16 + grp * 4 + q]
                           : Whh2[wr * 32 + (c - 4) * 16 + grp * 4 + q];
        f.u[q] = dup_bf(wv);
      }
      A2[c] = f.v;
    }
  }
  const int h2o = 4 * u + grp;
  float bias2[4];
#pragma unroll
  for (int r = 0; r < 4; ++r)
    bias2[r] = bih2[r * 32 + h2o] + bhh2[r * 32 + h2o];

  // ---- LDS init ----
  for (int i2 = tid; i2 < 4096; i2 += 512) sWo[i2] = Wout[i2];
  {
    unsigned short* z = &sh1[0][0][0];
    for (int i2 = tid; i2 < 2 * 16 * ROW1; i2 += 512) z[i2] = 0;
    unsigned short* z2 = &sh2[0][0][0];
    for (int i2 = tid; i2 < 2 * 16 * ROW2; i2 += 512) z2[i2] = 0;
  }
  for (int idx = tid; idx < 16 * 128 * 8; idx += 512) {
    int bb = idx >> 10, rem = idx & 1023;
    int t = rem >> 3, d = rem & 7;
    sxw[t * 128 + bb * 8 + d] = x1p[(size_t)(b0 + bb) * 1024 + rem];
  }
  __syncthreads();

  float c1[2] = {0.f, 0.f};
  float c2 = 0.f;
  float accO = 0.f;
  int cur = 0;

  for (int t = 0; t <= 128; ++t) {
    const bool doL1 = (t < 128);
    const bool doL2 = (t > 0);

    F8 s1f[5], s2f[2];
#pragma unroll
    for (int c = 0; c < 4; ++c)
      s1f[c].q = *(const uint4*)&sh1[cur][col][c * 32 + grp * 8];
#pragma unroll
    for (int c = 0; c < 2; ++c)
      s2f[c].q = *(const uint4*)&sh2[cur][col][c * 32 + grp * 8];
    if (doL1)
      s1f[4].q = *(const uint4*)&sxw[t * 128 + col * 8 + (grp & 1) * 4];

    if (doL1) {
      f32x4 acc[2];
#pragma unroll
      for (int jj = 0; jj < 2; ++jj) {
        f32x4 a = {0.f, 0.f, 0.f, 0.f};
#pragma unroll
        for (int c = 0; c < 5; ++c)
          a = __builtin_amdgcn_mfma_f32_16x16x32_bf16(A1[jj][c], s1f[c].v, a, 0, 0, 0);
        acc[jj] = a;
      }
      unsigned hp[2];
#pragma unroll
      for (int jj = 0; jj < 2; ++jj) {
        float ig = sigm(acc[jj][0]);
        float fg = sigm(acc[jj][1]);
        float tg = tanh_fast(acc[jj][2]);
        float og = sigm(acc[jj][3]);
        float cc = fg * c1[jj] + ig * tg;
        c1[jj] = cc;
        hp[jj] = split_pack(og * tanh_fast(cc));
      }
      uint2 hw = {hp[0], hp[1]};
      *(uint2*)&sh1[cur ^ 1][col][2 * (vw * 16 + 4 * grp + 2 * wsub)] = hw;
    }

    if (doL2) {
      f32x4 a = {bias2[0], bias2[1], bias2[2], bias2[3]};
#pragma unroll
      for (int c = 0; c < 4; ++c)
        a = __builtin_amdgcn_mfma_f32_16x16x32_bf16(A2[c], s1f[c].v, a, 0, 0, 0);
#pragma unroll
      for (int c = 0; c < 2; ++c)
        a = __builtin_amdgcn_mfma_f32_16x16x32_bf16(A2[4 + c], s2f[c].v, a, 0, 0, 0);
      float ig = sigm(a[0]);
      float fg = sigm(a[1]);
      float tg = tanh_fast(a[2]);
      float og = sigm(a[3]);
      float cc = fg * c2 + ig * tg;
      c2 = cc;
      float hn = og * tanh_fast(cc);
      accO += hn * sWo[(t - 1) * 32 + h2o];
      *(unsigned*)&sh2[cur ^ 1][col][2 * h2o] = split_pack(hn);
    }

    __syncthreads();
    cur ^= 1;
  }

  accO += __shfl_xor(accO, 16);
  accO += __shfl_xor(accO, 32);
  if (grp == 0) sOut[w][col] = accO;
  __syncthreads();
  if (tid < 16) {
    float s = bout[0];
#pragma unroll
    for (int ww = 0; ww < 8; ++ww) s += sOut[ww][tid];
    out[b0 + tid] = s;
  }
}

extern "C" void kernel_launch(void* const* d_in, const int* in_sizes, int n_in,
                              void* d_out, int out_size, void* d_ws, size_t ws_size,
                              hipStream_t stream) {
  const float* x    = (const float*)d_in[0];
  const float* tme  = (const float*)d_in[1];
  const float* Wc   = (const float*)d_in[2];
  const float* bc   = (const float*)d_in[3];
  const float* Wih1 = (const float*)d_in[4];
  const float* Whh1 = (const float*)d_in[5];
  const float* Wih2 = (const float*)d_in[6];
  const float* Whh2 = (const float*)d_in[7];
  const float* bih2 = (const float*)d_in[8];
  const float* bhh2 = (const float*)d_in[9];
  const float* Wout = (const float*)d_in[10];
  const float* bout = (const float*)d_in[11];
  float* outp = (float*)d_out;
  unsigned* x1p = (unsigned*)d_ws;  // [4096][1024] packed split-bf16 = 16.78 MB

  dim3 gA(16, 32);  // N/64, M/128
  combine_mfma<<<gA, 256, 0, stream>>>(x, tme, Wc, bc, x1p);

  const size_t smem = 65536 + 16384 + 8704 + 4608 + 8 * 16 * sizeof(float);
  hipFuncSetAttribute(reinterpret_cast<const void*>(lstm_fused_mfma),
                      hipFuncAttributeMaxDynamicSharedMemorySize, (int)smem);
  lstm_fused_mfma<<<256, 512, smem, stream>>>(x1p, Wih1, Whh1, Wih2, Whh2,
                                              bih2, bhh2, Wout, bout, outp);
}